// Round 1
// baseline (744.985 us; speedup 1.0000x reference)
//
#include <hip/hip_runtime.h>

#define NFEAT 256
#define DHEAD 64
#define NSEQ  4096
#define NBH   32

// 64^-0.25, 256^-0.5, 0.5*64^-0.5
constexpr float NORM_C  = 0.35355339059327373f;
constexpr float RATIO_C = 0.0625f;
constexpr float DIAG_C  = 0.0625f;
constexpr float KEPS_C  = 1e-4f;

__device__ __forceinline__ unsigned enc_f(float f) {
  unsigned u = __float_as_uint(f);
  return (u & 0x80000000u) ? ~u : (u | 0x80000000u);
}
__device__ __forceinline__ float dec_f(unsigned e) {
  return (e & 0x80000000u) ? __uint_as_float(e ^ 0x80000000u) : __uint_as_float(~e);
}

// ---------------------------------------------------------------------------
// Kernel A: global max of data_dash(k).  dd[n,j] = sum_d k[n,d]*(NORM*proj[j,d])
// Block: 256 thr. Per chunk: 32 rows x 256 j, K=64. Thread tile 4x8.
// Lane map: tj = w*8 + (lane&7) (j-group of 8), tn = lane>>3 (4 rows).
// a-frag broadcast conflict-free, b-frag 2-way (free).
// ---------------------------------------------------------------------------
__global__ __launch_bounds__(256, 2) void kmax_kernel(
    const float* __restrict__ kk, const float* __restrict__ proj,
    unsigned* __restrict__ kmax_u) {
  __shared__ __align__(16) float projT[DHEAD * NFEAT];  // [d][j] stride 256
  __shared__ __align__(16) float kT[DHEAD * 36];        // [d][n] stride 36
  __shared__ float wred[4];
  const int t = threadIdx.x;
  const int lane = t & 63;
  const int w = t >> 6;
  for (int i = t; i < NFEAT * DHEAD; i += 256)
    projT[(i & 63) * NFEAT + (i >> 6)] = NORM_C * proj[i];
  const int tj = w * 8 + (lane & 7);
  const int tn = lane >> 3;
  float mx = -3.0e38f;
  for (int chunk = blockIdx.x; chunk < (NBH * NSEQ / 32); chunk += gridDim.x) {
    const int head = chunk >> 7;
    const int row0 = (chunk & 127) << 5;
    const float* kb = kk + ((size_t)head * NSEQ + row0) * DHEAD;
    __syncthreads();  // protect kT vs prior iter readers (also projT ready, iter 0)
#pragma unroll
    for (int i = 0; i < 8; ++i) {          // coalesced transpose: d = lane
      const int r = w + (i << 2);
      kT[lane * 36 + r] = kb[r * DHEAD + lane];
    }
    __syncthreads();
    float acc[4][8];
#pragma unroll
    for (int i = 0; i < 4; ++i)
#pragma unroll
      for (int j = 0; j < 8; ++j) acc[i][j] = 0.f;
#pragma unroll 4
    for (int d = 0; d < DHEAD; ++d) {
      const float4 a  = *(const float4*)&kT[d * 36 + tn * 4];
      const float4 b0 = *(const float4*)&projT[d * NFEAT + tj * 8];
      const float4 b1 = *(const float4*)&projT[d * NFEAT + tj * 8 + 4];
      const float av[4] = {a.x, a.y, a.z, a.w};
      const float bv[8] = {b0.x, b0.y, b0.z, b0.w, b1.x, b1.y, b1.z, b1.w};
#pragma unroll
      for (int i = 0; i < 4; ++i)
#pragma unroll
        for (int j = 0; j < 8; ++j) acc[i][j] = fmaf(av[i], bv[j], acc[i][j]);
    }
#pragma unroll
    for (int i = 0; i < 4; ++i)
#pragma unroll
      for (int j = 0; j < 8; ++j) mx = fmaxf(mx, acc[i][j]);
  }
  for (int s = 1; s < 64; s <<= 1) mx = fmaxf(mx, __shfl_xor(mx, s));
  if (lane == 0) wred[w] = mx;
  __syncthreads();
  if (t == 0) {
    float m = fmaxf(fmaxf(wred[0], wred[1]), fmaxf(wred[2], wred[3]));
    atomicMax(kmax_u, enc_f(m));
  }
}

// ---------------------------------------------------------------------------
// Kernel B: kp = RATIO*(exp(dd_k - diag - m) + eps); ksum[j] += kp;
//           ctx[j,e] += kp[n,j]*v[n,e].  8 blocks/head, 512 rows each.
// ---------------------------------------------------------------------------
__global__ __launch_bounds__(256, 1) void kctx_kernel(
    const float* __restrict__ kk, const float* __restrict__ vv,
    const float* __restrict__ proj, const unsigned* __restrict__ kmax_u,
    float* __restrict__ ksum, float* __restrict__ ctx) {
  __shared__ __align__(16) float projT[DHEAD * NFEAT];  // 65536 B
  __shared__ __align__(16) float kT[DHEAD * 36];        // 9216 B
  __shared__ __align__(16) float kp[32 * NFEAT];        // 32768 B  [n][j]
  __shared__ __align__(16) float vt[32 * DHEAD];        // 8192 B   [n][e]
  __shared__ float diag[32];
  const int t = threadIdx.x;
  const int lane = t & 63;
  const int w = t >> 6;
  const int head = blockIdx.x >> 3;
  const int slab = blockIdx.x & 7;
  const float m = dec_f(*kmax_u);
  for (int i = t; i < NFEAT * DHEAD; i += 256)
    projT[(i & 63) * NFEAT + (i >> 6)] = NORM_C * proj[i];
  const int tj = w * 8 + (lane & 7);
  const int tn = lane >> 3;
  const int cj0 = w * 64 + tn * 8;   // ctx-GEMM j base (8 j per thread)
  const int ce0 = (lane & 7) * 8;    // ctx-GEMM e base (8 e per thread)
  float cacc[8][8];
#pragma unroll
  for (int j = 0; j < 8; ++j)
#pragma unroll
    for (int e = 0; e < 8; ++e) cacc[j][e] = 0.f;
  float ksp[8] = {0.f, 0.f, 0.f, 0.f, 0.f, 0.f, 0.f, 0.f};

  for (int c = 0; c < 16; ++c) {
    const int row0 = slab * 512 + c * 32;
    const float* kb = kk + ((size_t)head * NSEQ + row0) * DHEAD;
    const float* vb = vv + ((size_t)head * NSEQ + row0) * DHEAD;
    __syncthreads();  // prior ctx-GEMM done reading kp/vt; kT free
#pragma unroll
    for (int i = 0; i < 8; ++i) {
      const int r = w + (i << 2);
      const float val = kb[r * DHEAD + lane];
      kT[lane * 36 + r] = val;
      float s2 = val * val;                     // diag via wave reduce
      for (int s = 1; s < 64; s <<= 1) s2 += __shfl_xor(s2, s);
      if (lane == 0) diag[r] = DIAG_C * s2;
    }
    ((float4*)vt)[t]       = ((const float4*)vb)[t];
    ((float4*)vt)[t + 256] = ((const float4*)vb)[t + 256];
    __syncthreads();
    float acc[4][8];
#pragma unroll
    for (int i = 0; i < 4; ++i)
#pragma unroll
      for (int j = 0; j < 8; ++j) acc[i][j] = 0.f;
#pragma unroll 4
    for (int d = 0; d < DHEAD; ++d) {
      const float4 a  = *(const float4*)&kT[d * 36 + tn * 4];
      const float4 b0 = *(const float4*)&projT[d * NFEAT + tj * 8];
      const float4 b1 = *(const float4*)&projT[d * NFEAT + tj * 8 + 4];
      const float av[4] = {a.x, a.y, a.z, a.w};
      const float bv[8] = {b0.x, b0.y, b0.z, b0.w, b1.x, b1.y, b1.z, b1.w};
#pragma unroll
      for (int i = 0; i < 4; ++i)
#pragma unroll
        for (int j = 0; j < 8; ++j) acc[i][j] = fmaf(av[i], bv[j], acc[i][j]);
    }
#pragma unroll
    for (int i = 0; i < 4; ++i) {
      const float dg = diag[tn * 4 + i];
#pragma unroll
      for (int j = 0; j < 8; ++j) {
        const float kv = RATIO_C * (__expf(acc[i][j] - dg - m) + KEPS_C);
        acc[i][j] = kv;
        ksp[j] += kv;
      }
      *(float4*)&kp[(tn * 4 + i) * NFEAT + tj * 8] =
          make_float4(acc[i][0], acc[i][1], acc[i][2], acc[i][3]);
      *(float4*)&kp[(tn * 4 + i) * NFEAT + tj * 8 + 4] =
          make_float4(acc[i][4], acc[i][5], acc[i][6], acc[i][7]);
    }
    __syncthreads();  // kp visible
#pragma unroll 2
    for (int n = 0; n < 32; ++n) {
      const float4 a0 = *(const float4*)&kp[n * NFEAT + cj0];
      const float4 a1 = *(const float4*)&kp[n * NFEAT + cj0 + 4];
      const float4 b0 = *(const float4*)&vt[n * DHEAD + ce0];
      const float4 b1 = *(const float4*)&vt[n * DHEAD + ce0 + 4];
      const float av[8] = {a0.x, a0.y, a0.z, a0.w, a1.x, a1.y, a1.z, a1.w};
      const float bv[8] = {b0.x, b0.y, b0.z, b0.w, b1.x, b1.y, b1.z, b1.w};
#pragma unroll
      for (int j = 0; j < 8; ++j)
#pragma unroll
        for (int e = 0; e < 8; ++e) cacc[j][e] = fmaf(av[j], bv[e], cacc[j][e]);
    }
  }
  // ksum: reduce over tn (lanes xor 8/16/32 share tj)
#pragma unroll
  for (int j = 0; j < 8; ++j) {
    float s = ksp[j];
    s += __shfl_xor(s, 8);
    s += __shfl_xor(s, 16);
    s += __shfl_xor(s, 32);
    if (tn == 0) atomicAdd(&ksum[head * NFEAT + tj * 8 + j], s);
  }
#pragma unroll
  for (int j = 0; j < 8; ++j)
#pragma unroll
    for (int e = 0; e < 8; ++e)
      atomicAdd(&ctx[((size_t)head * NFEAT + cj0 + j) * DHEAD + ce0 + e],
                cacc[j][e]);
}

// ---------------------------------------------------------------------------
// Kernel C: qp (per-row max), d_inv = 1/(qp.ksum), out = (qp.ctx)*d_inv.
// out-GEMM splits K(j) over the 4 waves (j = 4k+w), LDS partial reduce.
// ---------------------------------------------------------------------------
__global__ __launch_bounds__(256, 1) void qout_kernel(
    const float* __restrict__ qq, const float* __restrict__ proj,
    const float* __restrict__ ksum, const float* __restrict__ ctx,
    float* __restrict__ out) {
  __shared__ __align__(16) float projT[DHEAD * NFEAT];  // 65536
  __shared__ __align__(16) float qT[DHEAD * 36];        // 9216
  __shared__ __align__(16) float qpT[NFEAT * 36];       // 36864  [j][n]
  __shared__ __align__(16) float ctile[32 * DHEAD];     // 8192   [j][e]
  __shared__ __align__(16) float part[4][32 * 68];      // 34816
  __shared__ __align__(16) float ksl[NFEAT];            // 1024
  __shared__ float diag[32];
  __shared__ float mpart[4][32];
  __shared__ float mrow[32];
  __shared__ float dpart[4][32];
  __shared__ float dinv[32];
  const int t = threadIdx.x;
  const int lane = t & 63;
  const int w = t >> 6;
  const int head = blockIdx.x >> 3;
  const int slab = blockIdx.x & 7;
  for (int i = t; i < NFEAT * DHEAD; i += 256)
    projT[(i & 63) * NFEAT + (i >> 6)] = NORM_C * proj[i];
  ksl[t] = ksum[head * NFEAT + t];
  const int tj = w * 8 + (lane & 7);
  const int tn = lane >> 3;
  const int ce0 = (lane & 7) * 8;
  const float* ctxh = ctx + (size_t)head * NFEAT * DHEAD;

  for (int c = 0; c < 16; ++c) {
    const int row0 = slab * 512 + c * 32;
    const float* qb = qq + ((size_t)head * NSEQ + row0) * DHEAD;
    __syncthreads();
#pragma unroll
    for (int i = 0; i < 8; ++i) {
      const int r = w + (i << 2);
      const float val = qb[r * DHEAD + lane];
      qT[lane * 36 + r] = val;
      float s2 = val * val;
      for (int s = 1; s < 64; s <<= 1) s2 += __shfl_xor(s2, s);
      if (lane == 0) diag[r] = DIAG_C * s2;
    }
    __syncthreads();
    float acc[4][8];
#pragma unroll
    for (int i = 0; i < 4; ++i)
#pragma unroll
      for (int j = 0; j < 8; ++j) acc[i][j] = 0.f;
#pragma unroll 4
    for (int d = 0; d < DHEAD; ++d) {
      const float4 a  = *(const float4*)&qT[d * 36 + tn * 4];
      const float4 b0 = *(const float4*)&projT[d * NFEAT + tj * 8];
      const float4 b1 = *(const float4*)&projT[d * NFEAT + tj * 8 + 4];
      const float av[4] = {a.x, a.y, a.z, a.w};
      const float bv[8] = {b0.x, b0.y, b0.z, b0.w, b1.x, b1.y, b1.z, b1.w};
#pragma unroll
      for (int i = 0; i < 4; ++i)
#pragma unroll
        for (int j = 0; j < 8; ++j) acc[i][j] = fmaf(av[i], bv[j], acc[i][j]);
    }
    // per-row max of data_dash
#pragma unroll
    for (int i = 0; i < 4; ++i) {
      float rm = acc[i][0];
#pragma unroll
      for (int j = 1; j < 8; ++j) rm = fmaxf(rm, acc[i][j]);
      rm = fmaxf(rm, __shfl_xor(rm, 1));
      rm = fmaxf(rm, __shfl_xor(rm, 2));
      rm = fmaxf(rm, __shfl_xor(rm, 4));
      if ((lane & 7) == 0) mpart[w][tn * 4 + i] = rm;
    }
    __syncthreads();
    if (t < 32)
      mrow[t] = fmaxf(fmaxf(mpart[0][t], mpart[1][t]),
                      fmaxf(mpart[2][t], mpart[3][t]));
    __syncthreads();
    // qp, d-partials, stage qpT
#pragma unroll
    for (int i = 0; i < 4; ++i) {
      const float mm = mrow[tn * 4 + i] + diag[tn * 4 + i];
      float s = 0.f;
#pragma unroll
      for (int j = 0; j < 8; ++j) {
        const float qv = RATIO_C * (__expf(acc[i][j] - mm) + KEPS_C);
        acc[i][j] = qv;
        s = fmaf(qv, ksl[tj * 8 + j], s);
      }
      s += __shfl_xor(s, 1);
      s += __shfl_xor(s, 2);
      s += __shfl_xor(s, 4);
      if ((lane & 7) == 0) dpart[w][tn * 4 + i] = s;
    }
#pragma unroll
    for (int j = 0; j < 8; ++j)
      *(float4*)&qpT[(tj * 8 + j) * 36 + tn * 4] =
          make_float4(acc[0][j], acc[1][j], acc[2][j], acc[3][j]);
    __syncthreads();
    if (t < 32)
      dinv[t] = 1.0f / (dpart[0][t] + dpart[1][t] + dpart[2][t] + dpart[3][t]);
    __syncthreads();
    // out-GEMM: wave w takes j = 4s+w within each 32-j ctx tile
    float oacc[4][8];
#pragma unroll
    for (int i = 0; i < 4; ++i)
#pragma unroll
      for (int e = 0; e < 8; ++e) oacc[i][e] = 0.f;
    for (int jb = 0; jb < 8; ++jb) {
      ((float4*)ctile)[t]       = ((const float4*)(ctxh + jb * 32 * DHEAD))[t];
      ((float4*)ctile)[t + 256] = ((const float4*)(ctxh + jb * 32 * DHEAD))[t + 256];
      __syncthreads();
#pragma unroll
      for (int s = 0; s < 8; ++s) {
        const int jl = s * 4 + w;
        const int j = jb * 32 + jl;
        const float4 a  = *(const float4*)&qpT[j * 36 + tn * 4];
        const float4 b0 = *(const float4*)&ctile[jl * DHEAD + ce0];
        const float4 b1 = *(const float4*)&ctile[jl * DHEAD + ce0 + 4];
        const float av[4] = {a.x, a.y, a.z, a.w};
        const float bv[8] = {b0.x, b0.y, b0.z, b0.w, b1.x, b1.y, b1.z, b1.w};
#pragma unroll
        for (int i = 0; i < 4; ++i)
#pragma unroll
          for (int e = 0; e < 8; ++e) oacc[i][e] = fmaf(av[i], bv[e], oacc[i][e]);
      }
      __syncthreads();  // tile consumed before next load
    }
#pragma unroll
    for (int i = 0; i < 4; ++i) {
      *(float4*)&part[w][(tn * 4 + i) * 68 + ce0] =
          make_float4(oacc[i][0], oacc[i][1], oacc[i][2], oacc[i][3]);
      *(float4*)&part[w][(tn * 4 + i) * 68 + ce0 + 4] =
          make_float4(oacc[i][4], oacc[i][5], oacc[i][6], oacc[i][7]);
    }
    __syncthreads();
    {
      const int n = t >> 3;
      const int e0 = (t & 7) * 8;
      float r[8];
#pragma unroll
      for (int e = 0; e < 8; ++e)
        r[e] = part[0][n * 68 + e0 + e] + part[1][n * 68 + e0 + e] +
               part[2][n * 68 + e0 + e] + part[3][n * 68 + e0 + e];
      const float di = dinv[n];
      float* ob = out + ((size_t)head * NSEQ + row0 + n) * DHEAD + e0;
      *(float4*)ob = make_float4(r[0] * di, r[1] * di, r[2] * di, r[3] * di);
      *(float4*)(ob + 4) = make_float4(r[4] * di, r[5] * di, r[6] * di, r[7] * di);
    }
  }
}

extern "C" void kernel_launch(void* const* d_in, const int* in_sizes, int n_in,
                              void* d_out, int out_size, void* d_ws, size_t ws_size,
                              hipStream_t stream) {
  (void)in_sizes; (void)n_in; (void)out_size; (void)ws_size;
  const float* q = (const float*)d_in[0];
  const float* k = (const float*)d_in[1];
  const float* v = (const float*)d_in[2];
  const float* proj = (const float*)d_in[3];
  float* out = (float*)d_out;
  unsigned char* ws = (unsigned char*)d_ws;
  unsigned* kmax_u = (unsigned*)ws;                       // 4 B (pad 128)
  float* ksum = (float*)(ws + 128);                       // 32*256 f32
  float* ctx  = (float*)(ws + 128 + NBH * NFEAT * 4);     // 32*256*64 f32
  const size_t zbytes = 128 + (size_t)NBH * NFEAT * 4 + (size_t)NBH * NFEAT * DHEAD * 4;
  hipMemsetAsync(d_ws, 0, zbytes, stream);
  hipLaunchKernelGGL(kmax_kernel, dim3(512), dim3(256), 0, stream, k, proj, kmax_u);
  hipLaunchKernelGGL(kctx_kernel, dim3(256), dim3(256), 0, stream, k, v, proj,
                     kmax_u, ksum, ctx);
  hipLaunchKernelGGL(qout_kernel, dim3(256), dim3(256), 0, stream, q, proj,
                     ksum, ctx, out);
}

// Round 2
// 363.287 us; speedup vs baseline: 2.0507x; 2.0507x over previous
//
#include <hip/hip_runtime.h>

#define NFEAT 256
#define DHEAD 64
#define NSEQ  4096
#define NHEADS 32

constexpr float NORM_C  = 0.35355339059327373f;  // 64^-0.25
constexpr float RATIO_C = 0.0625f;               // 256^-0.5
constexpr float DIAG_C  = 0.0625f;               // 0.5 * 64^-0.5
constexpr float KEPS_C  = 1e-4f;

using v8s = __attribute__((ext_vector_type(8))) short;
using v4f = __attribute__((ext_vector_type(4))) float;
union Frag8 { v8s v; ushort u[8]; };

__device__ __forceinline__ ushort bf16h(float x) {
  unsigned u = __float_as_uint(x);
  return (ushort)((u + 0x7FFFu + ((u >> 16) & 1)) >> 16);
}
__device__ __forceinline__ float bf16f(ushort h) {
  return __uint_as_float(((unsigned)h) << 16);
}
__device__ __forceinline__ unsigned enc_f(float f) {
  unsigned u = __float_as_uint(f);
  return (u & 0x80000000u) ? ~u : (u | 0x80000000u);
}
__device__ __forceinline__ float dec_f(unsigned e) {
  return (e & 0x80000000u) ? __uint_as_float(e ^ 0x80000000u) : __uint_as_float(~e);
}

#define MFMA(a, b, c) __builtin_amdgcn_mfma_f32_16x16x32_bf16((a), (b), (c), 0, 0, 0)

// split P (with NORM folded) into bf16 hi/lo planes, layout [j][d]
__global__ void prep_kernel(const float* __restrict__ proj,
                            ushort* __restrict__ Phi, ushort* __restrict__ Plo) {
  int i = blockIdx.x * 256 + threadIdx.x;
  if (i < NFEAT * DHEAD) {
    float x = NORM_C * proj[i];
    ushort h = bf16h(x);
    Phi[i] = h;
    Plo[i] = bf16h(x - bf16f(h));
  }
}

// ---------------------------------------------------------------------------
// kmax: global max of dd_k via MFMA.  Block = (head, slab of 256 rows).
// chunk 32 rows = 2 m-tiles; waves: (mw = w&1) x (jw = w>>1, j-half of 128).
// ---------------------------------------------------------------------------
__global__ __launch_bounds__(256, 2) void kmax_kernel(
    const float* __restrict__ kk, const ushort* __restrict__ Phi,
    const ushort* __restrict__ Plo, unsigned* __restrict__ kmax_u) {
  __shared__ float wred[4];
  const int t = threadIdx.x, lane = t & 63, w = t >> 6;
  const int cl = lane & 15, q = lane >> 4;
  const int mw = w & 1, jw = w >> 1;
  const int head = blockIdx.x >> 4, slab = blockIdx.x & 15;
  const float* kbase = kk + ((size_t)(head * NSEQ + slab * 256)) * DHEAD;
  float mx = -3.0e38f;
  for (int c = 0; c < 8; ++c) {
    const float* arow = kbase + (c * 32 + mw * 16 + cl) * DHEAD + q * 8;
    v4f acc[8];
#pragma unroll
    for (int jt = 0; jt < 8; ++jt) acc[jt] = (v4f){0.f, 0.f, 0.f, 0.f};
#pragma unroll
    for (int ks = 0; ks < 2; ++ks) {
      float4 a0 = *(const float4*)(arow + ks * 32);
      float4 a1 = *(const float4*)(arow + ks * 32 + 4);
      float af[8] = {a0.x, a0.y, a0.z, a0.w, a1.x, a1.y, a1.z, a1.w};
      Frag8 ah, al;
#pragma unroll
      for (int i = 0; i < 8; ++i) {
        ushort h = bf16h(af[i]);
        ah.u[i] = h;
        al.u[i] = bf16h(af[i] - bf16f(h));
      }
#pragma unroll
      for (int jt = 0; jt < 8; ++jt) {
        int j = jw * 128 + jt * 16 + cl;
        v8s bh = *(const v8s*)(Phi + j * 64 + ks * 32 + q * 8);
        v8s bl = *(const v8s*)(Plo + j * 64 + ks * 32 + q * 8);
        acc[jt] = MFMA(ah.v, bh, acc[jt]);
        acc[jt] = MFMA(ah.v, bl, acc[jt]);
        acc[jt] = MFMA(al.v, bh, acc[jt]);
      }
    }
#pragma unroll
    for (int jt = 0; jt < 8; ++jt)
#pragma unroll
      for (int r = 0; r < 4; ++r) mx = fmaxf(mx, acc[jt][r]);
  }
  for (int s = 1; s < 64; s <<= 1) mx = fmaxf(mx, __shfl_xor(mx, s));
  if (lane == 0) wred[w] = mx;
  __syncthreads();
  if (t == 0)
    atomicMax(kmax_u,
              enc_f(fmaxf(fmaxf(wred[0], wred[1]), fmaxf(wred[2], wred[3]))));
}

// ---------------------------------------------------------------------------
// kctx: dd_k -> kp (exp) -> LDS -> ctx += kp^T * v, ksum += kp.
// LDS rows stride 40 bf16 (80 B): b128 frag reads conflict-free, writes 2-way.
// ---------------------------------------------------------------------------
#define KPS 40
__global__ __launch_bounds__(256, 2) void kctx_kernel(
    const float* __restrict__ kk, const float* __restrict__ vv,
    const ushort* __restrict__ Phi, const ushort* __restrict__ Plo,
    const unsigned* __restrict__ kmax_u, float* __restrict__ ksum,
    float* __restrict__ ctx) {
  __shared__ __align__(16) ushort kphi[NFEAT * KPS];  // 20 KB  [j][n]
  __shared__ __align__(16) ushort kplo[NFEAT * KPS];  // 20 KB
  __shared__ __align__(16) ushort vthi[DHEAD * KPS];  // 5 KB   [e][n]
  __shared__ __align__(16) ushort vtlo[DHEAD * KPS];  // 5 KB
  __shared__ float diag[32];
  const int t = threadIdx.x, lane = t & 63, w = t >> 6;
  const int cl = lane & 15, q = lane >> 4;
  const int mw = w & 1, jw = w >> 1;
  const int head = blockIdx.x >> 4, slab = blockIdx.x & 15;
  const float m = dec_f(*kmax_u);
  float ksacc[8] = {0.f, 0.f, 0.f, 0.f, 0.f, 0.f, 0.f, 0.f};
  v4f ctxacc[4][4];
#pragma unroll
  for (int jj = 0; jj < 4; ++jj)
#pragma unroll
    for (int et = 0; et < 4; ++et) ctxacc[jj][et] = (v4f){0.f, 0.f, 0.f, 0.f};

  for (int c = 0; c < 8; ++c) {
    const int row0 = slab * 256 + c * 32;
    __syncthreads();  // kp/vt free (prev phase3 done)
    // stage v^T (bf16 hi/lo), layout [e][n]
    {
      int np = t >> 4, e0 = (t & 15) * 4;
      const float* vr = vv + ((size_t)(head * NSEQ + row0 + np * 2)) * DHEAD + e0;
      float4 va = *(const float4*)vr;
      float4 vb = *(const float4*)(vr + DHEAD);
      float fa[4] = {va.x, va.y, va.z, va.w};
      float fb[4] = {vb.x, vb.y, vb.z, vb.w};
#pragma unroll
      for (int cc = 0; cc < 4; ++cc) {
        int e = e0 + cc;
        ushort h0 = bf16h(fa[cc]), h1 = bf16h(fb[cc]);
        ushort l0 = bf16h(fa[cc] - bf16f(h0)), l1 = bf16h(fb[cc] - bf16f(h1));
        *(uint*)&vthi[e * KPS + np * 2] = (uint)h0 | ((uint)h1 << 16);
        *(uint*)&vtlo[e * KPS + np * 2] = (uint)l0 | ((uint)l1 << 16);
      }
    }
    // phase 1: dd_k tile via MFMA, split-on-load A
    const float* arow =
        kk + ((size_t)(head * NSEQ + row0 + mw * 16 + cl)) * DHEAD + q * 8;
    v4f acc[8];
#pragma unroll
    for (int jt = 0; jt < 8; ++jt) acc[jt] = (v4f){0.f, 0.f, 0.f, 0.f};
    float ssq = 0.f;
#pragma unroll
    for (int ks = 0; ks < 2; ++ks) {
      float4 a0 = *(const float4*)(arow + ks * 32);
      float4 a1 = *(const float4*)(arow + ks * 32 + 4);
      float af[8] = {a0.x, a0.y, a0.z, a0.w, a1.x, a1.y, a1.z, a1.w};
      Frag8 ah, al;
#pragma unroll
      for (int i = 0; i < 8; ++i) {
        ssq = fmaf(af[i], af[i], ssq);
        ushort h = bf16h(af[i]);
        ah.u[i] = h;
        al.u[i] = bf16h(af[i] - bf16f(h));
      }
#pragma unroll
      for (int jt = 0; jt < 8; ++jt) {
        int j = jw * 128 + jt * 16 + cl;
        v8s bh = *(const v8s*)(Phi + j * 64 + ks * 32 + q * 8);
        v8s bl = *(const v8s*)(Plo + j * 64 + ks * 32 + q * 8);
        acc[jt] = MFMA(ah.v, bh, acc[jt]);
        acc[jt] = MFMA(ah.v, bl, acc[jt]);
        acc[jt] = MFMA(al.v, bh, acc[jt]);
      }
    }
    {  // diag[row] = DIAG_C * sum(k^2)
      float s2 = ssq;
      s2 += __shfl_xor(s2, 16);
      s2 += __shfl_xor(s2, 32);
      if (jw == 0 && q == 0) diag[mw * 16 + cl] = DIAG_C * s2;
    }
    __syncthreads();
    // phase 2: kp = RATIO*(exp(dd - diag - m) + eps); store bf16 planes [j][n]
#pragma unroll
    for (int jt = 0; jt < 8; ++jt) {
      int j = jw * 128 + jt * 16 + cl;
      float kv[4];
#pragma unroll
      for (int r = 0; r < 4; ++r) {
        int row = mw * 16 + q * 4 + r;
        float e_ = RATIO_C * (__expf(acc[jt][r] - diag[row] - m) + KEPS_C);
        kv[r] = e_;
        ksacc[jt] += e_;
      }
#pragma unroll
      for (int p = 0; p < 2; ++p) {
        ushort h0 = bf16h(kv[2 * p]), h1 = bf16h(kv[2 * p + 1]);
        ushort l0 = bf16h(kv[2 * p] - bf16f(h0));
        ushort l1 = bf16h(kv[2 * p + 1] - bf16f(h1));
        int ui = j * KPS + mw * 16 + q * 4 + 2 * p;
        *(uint*)&kphi[ui] = (uint)h0 | ((uint)h1 << 16);
        *(uint*)&kplo[ui] = (uint)l0 | ((uint)l1 << 16);
      }
    }
    __syncthreads();
    // phase 3: ctx[j][e] += kp^T * v  (K = 32 = one k-step)
    v8s bhv[4], blv[4];
#pragma unroll
    for (int et = 0; et < 4; ++et) {
      int e = et * 16 + cl;
      bhv[et] = *(const v8s*)&vthi[e * KPS + q * 8];
      blv[et] = *(const v8s*)&vtlo[e * KPS + q * 8];
    }
#pragma unroll
    for (int jj = 0; jj < 4; ++jj) {
      int jrow = (w * 4 + jj) * 16 + cl;
      v8s ah2 = *(const v8s*)&kphi[jrow * KPS + q * 8];
      v8s al2 = *(const v8s*)&kplo[jrow * KPS + q * 8];
#pragma unroll
      for (int et = 0; et < 4; ++et) {
        ctxacc[jj][et] = MFMA(ah2, bhv[et], ctxacc[jj][et]);
        ctxacc[jj][et] = MFMA(ah2, blv[et], ctxacc[jj][et]);
        ctxacc[jj][et] = MFMA(al2, bhv[et], ctxacc[jj][et]);
      }
    }
  }
  // ksum: lane sums rows of its quad; combine quads via shuffle
#pragma unroll
  for (int jt = 0; jt < 8; ++jt) {
    float s = ksacc[jt];
    s += __shfl_xor(s, 16);
    s += __shfl_xor(s, 32);
    if (q == 0) atomicAdd(&ksum[head * NFEAT + jw * 128 + jt * 16 + cl], s);
  }
#pragma unroll
  for (int jj = 0; jj < 4; ++jj)
#pragma unroll
    for (int et = 0; et < 4; ++et)
#pragma unroll
      for (int r = 0; r < 4; ++r) {
        int j = (w * 4 + jj) * 16 + q * 4 + r;
        int e = et * 16 + cl;
        atomicAdd(&ctx[((size_t)head * NFEAT + j) * DHEAD + e],
                  ctxacc[jj][et][r]);
      }
}

// ---------------------------------------------------------------------------
// ctxprep: ctx fp32 [h][j][e] -> ctxT bf16 hi/lo planes [h][e][j]
// ---------------------------------------------------------------------------
__global__ void ctxprep_kernel(const float* __restrict__ ctx,
                               ushort* __restrict__ ctxThi,
                               ushort* __restrict__ ctxTlo) {
  __shared__ float tile[64 * 65];
  const int head = blockIdx.x >> 2, jb = blockIdx.x & 3, t = threadIdx.x;
#pragma unroll
  for (int i = 0; i < 16; ++i) {
    int idx = t + i * 256;
    int jj = idx >> 6, e = idx & 63;
    tile[jj * 65 + e] = ctx[((size_t)head * NFEAT + jb * 64 + jj) * DHEAD + e];
  }
  __syncthreads();
#pragma unroll
  for (int i = 0; i < 16; ++i) {
    int idx = t + i * 256;
    int e = idx >> 6, jj = idx & 63;
    float x = tile[jj * 65 + e];
    ushort h = bf16h(x);
    size_t o = ((size_t)head * DHEAD + e) * NFEAT + jb * 64 + jj;
    ctxThi[o] = h;
    ctxTlo[o] = bf16h(x - bf16f(h));
  }
}

// ---------------------------------------------------------------------------
// qout: dd_q -> rowmax -> qp -> LDS; d_inv; out = (qp . ctx) * d_inv
// qp LDS layout [n][j], row stride 264 bf16 (16B-aligned, conflict-free b128)
// ---------------------------------------------------------------------------
#define QPS 264
__global__ __launch_bounds__(256, 2) void qout_kernel(
    const float* __restrict__ qq, const ushort* __restrict__ Phi,
    const ushort* __restrict__ Plo, const float* __restrict__ ksum,
    const ushort* __restrict__ ctxThi, const ushort* __restrict__ ctxTlo,
    float* __restrict__ out) {
  __shared__ __align__(16) ushort qphi[32 * QPS];  // 16.5 KB
  __shared__ __align__(16) ushort qplo[32 * QPS];
  __shared__ float diag[32], mpart[2][32], dpart[2][32], dinv[32];
  const int t = threadIdx.x, lane = t & 63, w = t >> 6;
  const int cl = lane & 15, q = lane >> 4;
  const int mw = w & 1, jw = w >> 1;
  const int head = blockIdx.x >> 4, slab = blockIdx.x & 15;
  float ksl[8];
#pragma unroll
  for (int jt = 0; jt < 8; ++jt)
    ksl[jt] = ksum[head * NFEAT + jw * 128 + jt * 16 + cl];

  for (int c = 0; c < 8; ++c) {
    const int row0 = slab * 256 + c * 32;
    __syncthreads();  // qp/dinv free
    const float* arow =
        qq + ((size_t)(head * NSEQ + row0 + mw * 16 + cl)) * DHEAD + q * 8;
    v4f acc[8];
#pragma unroll
    for (int jt = 0; jt < 8; ++jt) acc[jt] = (v4f){0.f, 0.f, 0.f, 0.f};
    float ssq = 0.f;
#pragma unroll
    for (int ks = 0; ks < 2; ++ks) {
      float4 a0 = *(const float4*)(arow + ks * 32);
      float4 a1 = *(const float4*)(arow + ks * 32 + 4);
      float af[8] = {a0.x, a0.y, a0.z, a0.w, a1.x, a1.y, a1.z, a1.w};
      Frag8 ah, al;
#pragma unroll
      for (int i = 0; i < 8; ++i) {
        ssq = fmaf(af[i], af[i], ssq);
        ushort h = bf16h(af[i]);
        ah.u[i] = h;
        al.u[i] = bf16h(af[i] - bf16f(h));
      }
#pragma unroll
      for (int jt = 0; jt < 8; ++jt) {
        int j = jw * 128 + jt * 16 + cl;
        v8s bh = *(const v8s*)(Phi + j * 64 + ks * 32 + q * 8);
        v8s bl = *(const v8s*)(Plo + j * 64 + ks * 32 + q * 8);
        acc[jt] = MFMA(ah.v, bh, acc[jt]);
        acc[jt] = MFMA(ah.v, bl, acc[jt]);
        acc[jt] = MFMA(al.v, bh, acc[jt]);
      }
    }
    {
      float s2 = ssq;
      s2 += __shfl_xor(s2, 16);
      s2 += __shfl_xor(s2, 32);
      if (jw == 0 && q == 0) diag[mw * 16 + cl] = DIAG_C * s2;
    }
    // per-row max over this wave's j-half
#pragma unroll
    for (int r = 0; r < 4; ++r) {
      float mr = acc[0][r];
#pragma unroll
      for (int jt = 1; jt < 8; ++jt) mr = fmaxf(mr, acc[jt][r]);
      mr = fmaxf(mr, __shfl_xor(mr, 1));
      mr = fmaxf(mr, __shfl_xor(mr, 2));
      mr = fmaxf(mr, __shfl_xor(mr, 4));
      mr = fmaxf(mr, __shfl_xor(mr, 8));
      if (cl == 0) mpart[jw][mw * 16 + q * 4 + r] = mr;
    }
    __syncthreads();
    // exp, qp store, d_inv dot
#pragma unroll
    for (int r = 0; r < 4; ++r) {
      int row = mw * 16 + q * 4 + r;
      float mm = fmaxf(mpart[0][row], mpart[1][row]) + diag[row];
      float ds = 0.f;
#pragma unroll
      for (int jt = 0; jt < 8; ++jt) {
        float qv = RATIO_C * (__expf(acc[jt][r] - mm) + KEPS_C);
        ds = fmaf(qv, ksl[jt], ds);
        int j = jw * 128 + jt * 16 + cl;
        ushort h = bf16h(qv);
        qphi[row * QPS + j] = h;
        qplo[row * QPS + j] = bf16h(qv - bf16f(h));
      }
      ds += __shfl_xor(ds, 1);
      ds += __shfl_xor(ds, 2);
      ds += __shfl_xor(ds, 4);
      ds += __shfl_xor(ds, 8);
      if (cl == 0) dpart[jw][row] = ds;
    }
    __syncthreads();
    if (t < 32) dinv[t] = 1.0f / (dpart[0][t] + dpart[1][t]);
    __syncthreads();
    // phase 3: out = qp . ctxT, K = 256 (8 k-steps)
    const int mw3 = w & 1, ew = w >> 1;
    v4f oacc[2];
    oacc[0] = (v4f){0.f, 0.f, 0.f, 0.f};
    oacc[1] = (v4f){0.f, 0.f, 0.f, 0.f};
#pragma unroll
    for (int ks8 = 0; ks8 < 8; ++ks8) {
      int nrow = mw3 * 16 + cl;
      v8s ah = *(const v8s*)&qphi[nrow * QPS + ks8 * 32 + q * 8];
      v8s al = *(const v8s*)&qplo[nrow * QPS + ks8 * 32 + q * 8];
#pragma unroll
      for (int eti = 0; eti < 2; ++eti) {
        int e = (ew * 2 + eti) * 16 + cl;
        size_t co = ((size_t)head * DHEAD + e) * NFEAT + ks8 * 32 + q * 8;
        v8s bh = *(const v8s*)(ctxThi + co);
        v8s bl = *(const v8s*)(ctxTlo + co);
        oacc[eti] = MFMA(ah, bh, oacc[eti]);
        oacc[eti] = MFMA(ah, bl, oacc[eti]);
        oacc[eti] = MFMA(al, bh, oacc[eti]);
      }
    }
#pragma unroll
    for (int eti = 0; eti < 2; ++eti)
#pragma unroll
      for (int r = 0; r < 4; ++r) {
        int row = mw3 * 16 + q * 4 + r;
        int e = (ew * 2 + eti) * 16 + cl;
        out[((size_t)(head * NSEQ + row0 + row)) * DHEAD + e] =
            oacc[eti][r] * dinv[row];
      }
  }
}

extern "C" void kernel_launch(void* const* d_in, const int* in_sizes, int n_in,
                              void* d_out, int out_size, void* d_ws, size_t ws_size,
                              hipStream_t stream) {
  (void)in_sizes; (void)n_in; (void)out_size; (void)ws_size;
  const float* q = (const float*)d_in[0];
  const float* k = (const float*)d_in[1];
  const float* v = (const float*)d_in[2];
  const float* proj = (const float*)d_in[3];
  float* out = (float*)d_out;
  unsigned char* ws = (unsigned char*)d_ws;
  // ws layout
  unsigned* kmax_u = (unsigned*)ws;                    // @0
  float* ksum = (float*)(ws + 256);                    // 32 KB
  float* ctx = (float*)(ws + 33024);                   // 2 MB
  ushort* Phi = (ushort*)(ws + 2130176);               // 32 KB
  ushort* Plo = (ushort*)(ws + 2162944);               // 32 KB
  ushort* ctxThi = (ushort*)(ws + 2195712);            // 1 MB
  ushort* ctxTlo = (ushort*)(ws + 3244288);            // 1 MB -> end 4292864
  hipMemsetAsync(d_ws, 0, 2130176, stream);  // kmax_u + ksum + ctx
  hipLaunchKernelGGL(prep_kernel, dim3(64), dim3(256), 0, stream, proj, Phi, Plo);
  hipLaunchKernelGGL(kmax_kernel, dim3(512), dim3(256), 0, stream, k, Phi, Plo,
                     kmax_u);
  hipLaunchKernelGGL(kctx_kernel, dim3(512), dim3(256), 0, stream, k, v, Phi,
                     Plo, kmax_u, ksum, ctx);
  hipLaunchKernelGGL(ctxprep_kernel, dim3(128), dim3(256), 0, stream, ctx,
                     ctxThi, ctxTlo);
  hipLaunchKernelGGL(qout_kernel, dim3(512), dim3(256), 0, stream, q, Phi, Plo,
                     ksum, ctxThi, ctxTlo, out);
}